// Round 3
// baseline (189.198 us; speedup 1.0000x reference)
//
#include <hip/hip_runtime.h>

// ---------------------------------------------------------------------------
// EMLLocalMessageBlock on MI355X — round 5 (resubmit; round-2 bench failure
// was container acquisition, not kernel evidence — source audited for
// barrier-divergence/LDS-bounds/race classes, none present).
//   x@W1 = center@(W1a+W1c) + nbhd@(W1b-W1c) + rel@W1d + b1
//   update = [Sum_n g_n (A_n @ VoW)]/mass + (vb@oW)*(sg/mass) + ob
// K-permutation (torch-reshape scramble): slot k'=16r+t <-> c2 = r+9t;
// per (n2,r): shift n=(2*n2+r)%9, channels c=c0+t, c0=(n2*128+r)/9.
// All LDS tiles use row stride AW=152 elems (304 B = 76 dw = 12 mod 32:
// ds_read_b128 lanes 0..7 tile all 8 bank-groups -> conflict-free).
// Round-5 deltas:
//  * edge GEMM + message GEMM merged into one ks loop (A fragments read once
//    -> -144 ds_read_b128 per CU per n2).
//  * LDS atomicAdd sums (256 colliding DS atomics/n2) replaced by 64 packed
//    ds_write_b128 to disjoint [partial][slot][rr] slots; gate waves add the
//    two partials. (theory: SQ_LDS_BANK_CONFLICT==737280 was the atomics.)
// ---------------------------------------------------------------------------

#define USHORT unsigned short
#define AW 152

typedef __attribute__((ext_vector_type(8)))  __bf16 v8bf;
typedef __attribute__((ext_vector_type(8)))  USHORT v8u;
typedef __attribute__((ext_vector_type(16))) float  v16f;

__device__ __forceinline__ USHORT f2bf(float f) {
    unsigned v; __builtin_memcpy(&v, &f, 4);
    v += 0x7FFFu + ((v >> 16) & 1u);
    return (USHORT)(v >> 16);
}

// ---- DPP helpers: pure-VALU cross-lane sums (DS pipe stays free) ----------
template <int C>
__device__ __forceinline__ float dpps(float x) {
    return __int_as_float(
        __builtin_amdgcn_update_dpp(0, __float_as_int(x), C, 0xf, 0xf, true));
}
// sum of lanes 0..31 lands in lane 31; sum of lanes 32..63 lands in lane 63
__device__ __forceinline__ float red32half(float x) {
    x += dpps<0x111>(x);   // row_shr:1
    x += dpps<0x112>(x);   // row_shr:2
    x += dpps<0x114>(x);   // row_shr:4
    x += dpps<0x118>(x);   // row_shr:8
    x += dpps<0x142>(x);   // row_bcast:15
    return x;
}
// full 64-lane sum lands in lane 63
__device__ __forceinline__ float red64(float x) {
    x = red32half(x);
    x += dpps<0x143>(x);   // row_bcast:31
    return x;
}
__device__ __forceinline__ float bcast63(float x) {
    return __int_as_float(__builtin_amdgcn_readlane(__float_as_int(x), 63));
}

// ---------------------------------------------------------------------------
// k_setup: blocks [0,354) = weight prep, blocks [354,8546) = LN1.
// (byte-identical — non-k_edge residual is harness-constant ~98 us)
// ---------------------------------------------------------------------------
__global__ __launch_bounds__(256) void k_setup(
    const float* __restrict__ tok, const float* __restrict__ ln1g,
    const float* __restrict__ ln1b,
    const float* __restrict__ dW1, const float* __restrict__ db1,
    const float* __restrict__ rW1, const float* __restrict__ rb1,
    const float* __restrict__ rel, const float* __restrict__ dW2,
    const float* __restrict__ rW2, const float* __restrict__ vW,
    const float* __restrict__ vb,  const float* __restrict__ oW,
    USHORT* __restrict__ norm,
    USHORT* __restrict__ WnTg, USHORT* __restrict__ WcTg, USHORT* __restrict__ VTg,
    float* __restrict__ preg, float* __restrict__ vboWg, float* __restrict__ w2g)
{
    const int blk = blockIdx.x, t = threadIdx.x;
    if (blk >= 354) {                     // ---- LN1 ----
        const int p = (blk - 354) * 4 + (t >> 6);
        const int lane = t & 63;
        const float2 x = ((const float2*)(tok + (size_t)p * 128))[lane];
        float s = x.x + x.y;
        for (int m = 1; m < 64; m <<= 1) s += __shfl_xor(s, m);
        const float mean = s * (1.f / 128.f);
        const float d0 = x.x - mean, d1 = x.y - mean;
        float q = d0 * d0 + d1 * d1;
        for (int m = 1; m < 64; m <<= 1) q += __shfl_xor(q, m);
        const float rstd = rsqrtf(q * (1.f / 128.f) + 1e-5f);
        const float2 gg = ((const float2*)ln1g)[lane], bb = ((const float2*)ln1b)[lane];
        ((unsigned*)norm)[(size_t)p * 64 + lane] =
            (unsigned)f2bf(d0 * rstd * gg.x + bb.x) |
            ((unsigned)f2bf(d1 * rstd * gg.y + bb.y) << 16);
        return;
    }
    if (blk < 72) {                       // VTg [128][144] = perm(vW@oW)^T
        int idx = blk * 256 + t;
        int n = ((idx >> 4) * 7282) >> 16;
        int k = idx - n * 144;
        int r = k >> 4, tt = k & 15, c2 = r + 9 * tt;
        float acc = 0.f;
        if (c2 < 128)
            for (int j = 0; j < 128; ++j) acc += vW[c2 * 128 + j] * oW[j * 128 + n];
        VTg[idx] = f2bf(acc);
    } else if (blk < 216) {               // WnTg [256][144] = perm(W1b-W1c)^T
        int idx = (blk - 72) * 256 + t;
        int n = ((idx >> 4) * 7282) >> 16;
        int k = idx - n * 144;
        int r = k >> 4, tt = k & 15, c2 = r + 9 * tt;
        int col = n & 127;
        const float* W = (n < 128) ? dW1 : rW1;
        float val = 0.f;
        if (c2 < 128) val = W[(128 + c2) * 128 + col] - W[(256 + c2) * 128 + col];
        WnTg[idx] = f2bf(val);
    } else if (blk < 344) {               // WcTg [256][128] = (W1a+W1c)^T
        int idx = (blk - 216) * 256 + t;
        int n = idx >> 7, c = idx & 127, col = n & 127;
        const float* W = (n < 128) ? dW1 : rW1;
        WcTg[idx] = f2bf(W[c * 128 + col] + W[(256 + c) * 128 + col]);
    } else if (blk < 353) {               // preg[9][256] = rel@W1d + b1
        int n2 = blk - 344; int h = t;
        float acc;
        if (h < 128) {
            acc = db1[h];
            for (int r = 0; r < 8; ++r) acc += rel[n2 * 8 + r] * dW1[(384 + r) * 128 + h];
        } else {
            int hh = h - 128;
            acc = rb1[hh];
            for (int r = 0; r < 8; ++r) acc += rel[n2 * 8 + r] * rW1[(384 + r) * 128 + hh];
        }
        preg[n2 * 256 + h] = acc;
    } else {
        if (t < 128) {
            float acc = 0.f;
            for (int j = 0; j < 128; ++j) acc += vb[j] * oW[j * 128 + t];
            vboWg[t] = acc;
            w2g[t] = dW2[t];
            w2g[128 + t] = rW2[t];
        }
    }
}

// ---------------------------------------------------------------------------
// gather split (T14): issue global loads early into regs, LDS-write later.
// ---------------------------------------------------------------------------
__device__ __forceinline__ void gather_load(
    uint2 (&pf)[9], const USHORT* __restrict__ nb,
    int n2, int y, int bI, int tid)
{
    const int x = tid >> 2, q = tid & 3;
    #pragma unroll
    for (int r = 0; r < 9; ++r) {
        int u = 2 * n2 + r;
        int n = (u >= 18) ? (u - 18) : ((u >= 9) ? (u - 9) : u);
        int v = n2 * 128 + r;
        int c0 = (v * 7282) >> 16;                 // v/9
        int dyq = (n * 22) >> 6;                   // n/3
        int dx = n - 3 * dyq - 1;
        int dy = dyq - 1;
        int sy = y + dy, sx = x + dx;
        bool ok = ((unsigned)sy < 128u) && ((unsigned)sx < 128u);
        int e0 = (c0 & ~1) + 4 * q;
        size_t gidx = ((size_t)((bI * 128 + (ok ? sy : 0)) * 128 + (ok ? sx : 0))) * 128 + e0;
        const unsigned* gp = (const unsigned*)nb + (gidx >> 1);
        unsigned dw0 = gp[0], dw1 = gp[1];
        pf[r].x = ok ? dw0 : 0u;
        pf[r].y = ok ? dw1 : 0u;
    }
}

__device__ __forceinline__ void gather_store(
    USHORT* __restrict__ Ash, const uint2 (&pf)[9], int n2, int tid)
{
    const int x = tid >> 2, q = tid & 3;
    #pragma unroll
    for (int r = 0; r < 9; ++r) {
        int v = n2 * 128 + r;
        int c0 = (v * 7282) >> 16;
        unsigned dw0 = pf[r].x, dw1 = pf[r].y;
        unsigned nxt = (unsigned)__shfl_down((int)dw0, 1);   // feeds slot15 (zero-wt)
        unsigned o0, o1;
        if (c0 & 1) { o0 = (dw0 >> 16) | (dw1 << 16); o1 = (dw1 >> 16) | (nxt << 16); }
        else        { o0 = dw0;                       o1 = dw1; }
        *(uint2*)(Ash + x * AW + 16 * r + 4 * q) = make_uint2(o0, o1);
    }
}

// ---------------------------------------------------------------------------
// k_edge: 256 blocks (one image row each), 512 threads = 8 waves = 2M x 4N.
// MFMA 32x32x16 bf16; C/D: col=lane&31, row=(reg&3)+8*(reg>>2)+4*(lane>>5).
// LDS 159744 B: Wsh[256][152] | Ash[128][152] | VTl[128][152] | w2L |
//               dP[2][8][16] | rP[2][8][16] | gateL[128] | sgL[128]
// Per-n2 barriers: A (partials written, Ash reads done), B (gate + Ash(n2+1))
// ---------------------------------------------------------------------------
__global__ __launch_bounds__(512, 2) void k_edge(
    const float* __restrict__ tok, const float* __restrict__ ln2g,
    const float* __restrict__ ln2b, const USHORT* __restrict__ nb,
    const USHORT* __restrict__ WnTg, const USHORT* __restrict__ WcTg,
    const USHORT* __restrict__ VTg, const float* __restrict__ preg,
    const float* __restrict__ vboWg, const float* __restrict__ w2g,
    const float* __restrict__ db2p, const float* __restrict__ rb2p,
    const float* __restrict__ gmp, const float* __restrict__ lmp,
    const float* __restrict__ bip, const float* __restrict__ obp,
    float* __restrict__ out)
{
    extern __shared__ char smem[];
    USHORT* Wsh  = (USHORT*)smem;                    // [256][152] = 77824
    USHORT* Ash  = (USHORT*)(smem + 77824);          // [128][152] = 38912
    USHORT* VTl  = (USHORT*)(smem + 116736);         // [128][152] = 38912
    float*  w2L  = (float*)(smem + 155648);          // 256 f32 = 1024
    float*  dP   = (float*)(smem + 156672);          // [2][8][16] f32 = 1024
    float*  rP   = (float*)(smem + 157696);          // [2][8][16] f32 = 1024
    float*  gateL= (float*)(smem + 158720);          // 128 f32 = 512
    float*  sgL  = (float*)(smem + 159232);          // end 159744
    float*  updF = (float*)smem;                     // final alias (64 KB)

    const int tid = threadIdx.x;
    const int lane = tid & 63, wave = tid >> 6, hi = lane >> 5, l31 = lane & 31;
    const int mw = wave & 1, nw = wave >> 1;
    const int blk = blockIdx.x;
    const int bI = blk >> 7;
    const int y = ((blk & 7) << 4) | ((blk >> 3) & 15);   // XCD band swizzle
    const int p0 = (bI * 128 + y) * 128;

    // ---- stage Wc + center A + VoW + w2 ----
    for (int i = tid; i < 4096; i += 512) {
        int n = i >> 4, kv = i & 15;
        *(v8u*)(Wsh + n * AW + kv * 8) = *(const v8u*)(WcTg + n * 128 + kv * 8);
    }
    for (int i = tid; i < 2048; i += 512) {
        int x = i >> 4, kv = i & 15;
        *(v8u*)(Ash + x * AW + kv * 8) = *(const v8u*)(nb + (size_t)(p0 + x) * 128 + kv * 8);
    }
    for (int i = tid; i < 2304; i += 512) {
        int n = (i * 3641) >> 16;                    // i/18
        int kv = i - n * 18;
        *(v8u*)(VTl + n * AW + kv * 8) = *(const v8u*)(VTg + n * 144 + kv * 8);
    }
    if (tid < 256) w2L[tid] = w2g[tid];
    if (tid < 128) sgL[tid] = 0.f;
    __syncthreads();

    // ---- center GEMM (K=128) ----
    v16f cp[2][2];
    #pragma unroll
    for (int a = 0; a < 2; ++a)
        for (int b = 0; b < 2; ++b)
            for (int e = 0; e < 16; ++e) cp[a][b][e] = 0.f;
    #pragma unroll
    for (int ks = 0; ks < 8; ++ks) {
        v8bf af0 = *(const v8bf*)(Ash + (mw * 64 + l31) * AW + ks * 16 + hi * 8);
        v8bf af1 = *(const v8bf*)(Ash + (mw * 64 + 32 + l31) * AW + ks * 16 + hi * 8);
        v8bf bf0 = *(const v8bf*)(Wsh + (nw * 64 + l31) * AW + ks * 16 + hi * 8);
        v8bf bf1 = *(const v8bf*)(Wsh + (nw * 64 + 32 + l31) * AW + ks * 16 + hi * 8);
        cp[0][0] = __builtin_amdgcn_mfma_f32_32x32x16_bf16(af0, bf0, cp[0][0], 0, 0, 0);
        cp[0][1] = __builtin_amdgcn_mfma_f32_32x32x16_bf16(af0, bf1, cp[0][1], 0, 0, 0);
        cp[1][0] = __builtin_amdgcn_mfma_f32_32x32x16_bf16(af1, bf0, cp[1][0], 0, 0, 0);
        cp[1][1] = __builtin_amdgcn_mfma_f32_32x32x16_bf16(af1, bf1, cp[1][1], 0, 0, 0);
    }
    __syncthreads();

    // ---- stage permuted Wn over Wc; first gather (reg round-trip) ----
    for (int i = tid; i < 4608; i += 512) {
        int n = (i * 3641) >> 16;
        int kv = i - n * 18;
        *(v8u*)(Wsh + n * AW + kv * 8) = *(const v8u*)(WnTg + n * 144 + kv * 8);
    }
    {
        uint2 pf0[9];
        gather_load(pf0, nb, 0, y, bI, tid);
        gather_store(Ash, pf0, 0, tid);
    }

    const float gmv = gmp[0], lmv = lmp[0], biv = bip[0];
    const float db2v = db2p[0], rb2v = rb2p[0];
    const float wv0 = w2L[nw * 64 + l31];
    const float wv1 = w2L[nw * 64 + 32 + l31];

    v16f acc3[2];
    #pragma unroll
    for (int a = 0; a < 2; ++a)
        for (int e = 0; e < 16; ++e) acc3[a][e] = 0.f;

    // partial-sum slot base for this wave's lanes 31/63 (f32 index)
    float* sumBase = ((nw < 2) ? dP : rP) + (nw & 1) * 128;

    __syncthreads();                      // pre-loop: Wn + Ash(0) ready

    for (int n2 = 0; n2 < 9; ++n2) {
        const float pv0 = preg[n2 * 256 + nw * 64 + l31];
        const float pv1 = preg[n2 * 256 + nw * 64 + 32 + l31];

        // prefetch next tile's global loads NOW — latency hides under MFMA
        uint2 pf[9];
        if (n2 < 8) gather_load(pf, nb, n2 + 1, y, bI, tid);

        // ---- merged GEMM: acc = cp + A@Wn (edge) ; P = A@VoW (message) ----
        v16f acc[2][2];
        #pragma unroll
        for (int a = 0; a < 2; ++a)
            for (int b = 0; b < 2; ++b) acc[a][b] = cp[a][b];
        v16f P[2];
        #pragma unroll
        for (int a = 0; a < 2; ++a)
            for (int e = 0; e < 16; ++e) P[a][e] = 0.f;
        #pragma unroll
        for (int ks = 0; ks < 9; ++ks) {
            v8bf af0 = *(const v8bf*)(Ash + (mw * 64 + l31) * AW + ks * 16 + hi * 8);
            v8bf af1 = *(const v8bf*)(Ash + (mw * 64 + 32 + l31) * AW + ks * 16 + hi * 8);
            v8bf bf0 = *(const v8bf*)(Wsh + (nw * 64 + l31) * AW + ks * 16 + hi * 8);
            v8bf bf1 = *(const v8bf*)(Wsh + (nw * 64 + 32 + l31) * AW + ks * 16 + hi * 8);
            v8bf vf  = *(const v8bf*)(VTl + (nw * 32 + l31) * AW + ks * 16 + hi * 8);
            acc[0][0] = __builtin_amdgcn_mfma_f32_32x32x16_bf16(af0, bf0, acc[0][0], 0, 0, 0);
            acc[0][1] = __builtin_amdgcn_mfma_f32_32x32x16_bf16(af0, bf1, acc[0][1], 0, 0, 0);
            acc[1][0] = __builtin_amdgcn_mfma_f32_32x32x16_bf16(af1, bf0, acc[1][0], 0, 0, 0);
            acc[1][1] = __builtin_amdgcn_mfma_f32_32x32x16_bf16(af1, bf1, acc[1][1], 0, 0, 0);
            P[0] = __builtin_amdgcn_mfma_f32_32x32x16_bf16(af0, vf, P[0], 0, 0, 0);
            P[1] = __builtin_amdgcn_mfma_f32_32x32x16_bf16(af1, vf, P[1], 0, 0, 0);
        }
        // ---- epilogue: gelu(h)·w2, DPP half-wave reduce, packed b128 write ----
        #pragma unroll
        for (int mt = 0; mt < 2; ++mt) {
            float part[16];
            #pragma unroll
            for (int rr = 0; rr < 16; ++rr) {
                float h0 = acc[mt][0][rr] + pv0;
                float h1 = acc[mt][1][rr] + pv1;
                float s0 = __builtin_amdgcn_rcpf(1.f + __expf(-1.702f * h0));
                float s1 = __builtin_amdgcn_rcpf(1.f + __expf(-1.702f * h1));
                part[rr] = h0 * s0 * wv0 + h1 * s1 * wv1;
            }
            #pragma unroll
            for (int rr = 0; rr < 16; ++rr) part[rr] = red32half(part[rr]);
            if (l31 == 31) {              // lanes 31 (hi=0) and 63 (hi=1)
                float* t0 = sumBase + ((mw * 2 + mt) * 2 + hi) * 16;
                *(float4*)(t0 +  0) = make_float4(part[0],  part[1],  part[2],  part[3]);
                *(float4*)(t0 +  4) = make_float4(part[4],  part[5],  part[6],  part[7]);
                *(float4*)(t0 +  8) = make_float4(part[8],  part[9],  part[10], part[11]);
                *(float4*)(t0 + 12) = make_float4(part[12], part[13], part[14], part[15]);
            }
        }
        __syncthreads();                  // A: partials written, Ash reads done
        if (n2 < 8) gather_store(Ash, pf, n2 + 1, tid);   // regs -> LDS
        if (tid < 128) {
            // row t -> packed slot: slot=((mw*2+mt)*2+hi)*16+rr
            int w32 = tid & 31;
            int slot = (((tid >> 6) * 2 + ((tid >> 5) & 1)) * 2 + ((w32 >> 2) & 1)) * 16
                       + ((w32 & 3) | (((w32 >> 3) & 3) << 2));
            float d = dP[slot] + dP[128 + slot] + db2v;
            float rr = rP[slot] + rP[128 + slot] + rb2v;
            float sp = fmaxf(rr, 0.f) + log1pf(__expf(-fabsf(rr)));
            float e = gmv * d / (lmv * sp + 1e-6f) + biv;
            e = fminf(fmaxf(e, -3.f), 3.f);
            float gt = 1.f / (1.f + __expf(-e));
            gateL[tid] = gt; sgL[tid] += gt;
        }
        __syncthreads();                  // B: gate + Ash(n2+1) ready
        // ---- acc3 += g ⊙ P (broadcast float4 gate reads) ----
        #pragma unroll
        for (int mt = 0; mt < 2; ++mt) {
            const float4* gq = (const float4*)&gateL[mw * 64 + mt * 32 + 4 * hi];
            float4 ga = gq[0], gb = gq[2], gc = gq[4], gd = gq[6];
            float gs[16] = {ga.x, ga.y, ga.z, ga.w, gb.x, gb.y, gb.z, gb.w,
                            gc.x, gc.y, gc.z, gc.w, gd.x, gd.y, gd.z, gd.w};
            #pragma unroll
            for (int rr = 0; rr < 16; ++rr) acc3[mt][rr] += gs[rr] * P[mt][rr];
        }
    }

    // ---- final: mass, update, LN2 (dP/rP repurposed as inv-mass, sg/mass) ----
    __syncthreads();
    if (tid < 128) {
        float s = sgL[tid];
        float m = fmaxf(s, 1e-6f);
        dP[tid] = 1.f / m;       // 1/mass
        rP[tid] = s / m;         // sg/mass
    }
    __syncthreads();

    {
        const int colc = nw * 32 + l31;
        const float vbw = vboWg[colc], obv = obp[colc];
        #pragma unroll
        for (int mt = 0; mt < 2; ++mt) {
            const int base = mw * 64 + mt * 32 + 4 * hi;
            const float4* iq = (const float4*)&dP[base];
            const float4* sq = (const float4*)&rP[base];
            float4 ia = iq[0], ib = iq[2], ic = iq[4], id = iq[6];
            float4 sa = sq[0], sb = sq[2], sc = sq[4], sd = sq[6];
            float iv[16] = {ia.x, ia.y, ia.z, ia.w, ib.x, ib.y, ib.z, ib.w,
                            ic.x, ic.y, ic.z, ic.w, id.x, id.y, id.z, id.w};
            float sv[16] = {sa.x, sa.y, sa.z, sa.w, sb.x, sb.y, sb.z, sb.w,
                            sc.x, sc.y, sc.z, sc.w, sd.x, sd.y, sd.z, sd.w};
            #pragma unroll
            for (int rr = 0; rr < 16; ++rr) {
                int row = base + (rr & 3) + 8 * (rr >> 2);
                updF[row * 128 + colc] = acc3[mt][rr] * iv[rr] + vbw * sv[rr] + obv;
            }
        }
    }
    __syncthreads();

    const float g20 = ln2g[lane], g21 = ln2g[lane + 64];
    const float b20 = ln2b[lane], b21 = ln2b[lane + 64];
    for (int q2 = 0; q2 < 16; ++q2) {
        int p = wave * 16 + q2;
        size_t gp = (size_t)(p0 + p) * 128;
        float x0 = tok[gp + lane]      + updF[p * 128 + lane];
        float x1 = tok[gp + lane + 64] + updF[p * 128 + lane + 64];
        float mean = bcast63(red64(x0 + x1)) * (1.f / 128.f);
        float d0 = x0 - mean, d1 = x1 - mean;
        float rstd = rsqrtf(bcast63(red64(d0 * d0 + d1 * d1)) * (1.f / 128.f) + 1e-5f);
        out[gp + lane]      = d0 * rstd * g20 + b20;
        out[gp + lane + 64] = d1 * rstd * g21 + b21;
    }
}

// ---------------------------------------------------------------------------
extern "C" void kernel_launch(void* const* d_in, const int* in_sizes, int n_in,
                              void* d_out, int out_size, void* d_ws, size_t ws_size,
                              hipStream_t stream) {
    const float* tok  = (const float*)d_in[0];
    const float* ln1g = (const float*)d_in[1];
    const float* ln1b = (const float*)d_in[2];
    const float* ln2g = (const float*)d_in[3];
    const float* ln2b = (const float*)d_in[4];
    const float* rel  = (const float*)d_in[5];
    const float* dW1  = (const float*)d_in[6];
    const float* db1  = (const float*)d_in[7];
    const float* dW2  = (const float*)d_in[8];
    const float* db2  = (const float*)d_in[9];
    const float* rW1  = (const float*)d_in[10];
    const float* rb1  = (const float*)d_in[11];
    const float* rW2  = (const float*)d_in[12];
    const float* rb2  = (const float*)d_in[13];
    const float* vW   = (const float*)d_in[14];
    const float* vb   = (const float*)d_in[15];
    const float* oW   = (const float*)d_in[16];
    const float* ob   = (const float*)d_in[17];
    const float* gm   = (const float*)d_in[18];
    const float* lm   = (const float*)d_in[19];
    const float* bi   = (const float*)d_in[20];
    float* out = (float*)d_out;

    char* w = (char*)d_ws;
    USHORT* norm = (USHORT*)w; w += 8388608;   // [32768][128] bf16
    USHORT* WnTg = (USHORT*)w; w += 73728;     // [256][144] bf16, permuted+zero-pad
    USHORT* WcTg = (USHORT*)w; w += 65536;     // [256][128] bf16
    USHORT* VTg  = (USHORT*)w; w += 36864;     // [128][144] bf16, permuted+zero-pad
    float*  preg = (float*)w;  w += 9216;      // [9][256] f32
    float*  vboWg= (float*)w;  w += 512;       // [128] f32
    float*  w2g  = (float*)w;  w += 1024;      // [256] f32

    hipFuncSetAttribute((const void*)k_edge,
                        hipFuncAttributeMaxDynamicSharedMemorySize, 159744);

    hipLaunchKernelGGL(k_setup, dim3(8546), dim3(256), 0, stream,
                       tok, ln1g, ln1b, dW1, db1, rW1, rb1, rel, dW2, rW2,
                       vW, vb, oW, norm, WnTg, WcTg, VTg, preg, vboWg, w2g);
    hipLaunchKernelGGL(k_edge, dim3(256), dim3(512), 159744, stream,
                       tok, ln2g, ln2b, norm, WnTg, WcTg, VTg, preg, vboWg, w2g,
                       db2, rb2, gm, lm, bi, ob, out);
}

// Round 4
// 185.779 us; speedup vs baseline: 1.0184x; 1.0184x over previous
//
#include <hip/hip_runtime.h>

// ---------------------------------------------------------------------------
// EMLLocalMessageBlock on MI355X — round 6.
//   x@W1 = center@(W1a+W1c) + nbhd@(W1b-W1c) + rel@W1d + b1
//   update = [(Σ_n g_n A_n) @ VoW]/mass + (vb@oW)*(sg/mass) + ob
// LINEARITY: VoW is n2-independent, so the gated message is computed as
// G = Σ_n g_n⊙A_n accumulated in registers (36 f32/thread), then ONE
// message GEMM after the n2 loop. Removes 144 MFMA/wave + P/acc3 regs
// (round-5's merged-GEMM spill: 290 live regs > 256 → 16KB/block scratch).
// K-permutation (torch-reshape scramble): slot k'=16r+t <-> c2 = r+9t
// (n2-independent); per (n2,r): shift n=(2*n2+r)%9, c=c0+t, c0=(n2*128+r)/9.
// LDS row stride AW=152 elems (304 B: 76 dw = 12 mod 32 -> b128 conflict-free).
// Ash double-buffered: gather_store(n2+1) -> Anxt while G-accum reads Acur.
// ---------------------------------------------------------------------------

#define USHORT unsigned short
#define AW 152

typedef __attribute__((ext_vector_type(8)))  __bf16 v8bf;
typedef __attribute__((ext_vector_type(8)))  USHORT v8u;
typedef __attribute__((ext_vector_type(16))) float  v16f;

__device__ __forceinline__ USHORT f2bf(float f) {
    unsigned v; __builtin_memcpy(&v, &f, 4);
    v += 0x7FFFu + ((v >> 16) & 1u);
    return (USHORT)(v >> 16);
}

// ---- DPP helpers: pure-VALU cross-lane sums ----
template <int C>
__device__ __forceinline__ float dpps(float x) {
    return __int_as_float(
        __builtin_amdgcn_update_dpp(0, __float_as_int(x), C, 0xf, 0xf, true));
}
__device__ __forceinline__ float red32half(float x) {
    x += dpps<0x111>(x);
    x += dpps<0x112>(x);
    x += dpps<0x114>(x);
    x += dpps<0x118>(x);
    x += dpps<0x142>(x);
    return x;                 // lanes 31 / 63 hold their half-sums
}
__device__ __forceinline__ float red64(float x) {
    x = red32half(x);
    x += dpps<0x143>(x);      // lane 63 holds full sum
    return x;
}
__device__ __forceinline__ float bcast63(float x) {
    return __int_as_float(__builtin_amdgcn_readlane(__float_as_int(x), 63));
}

// ---------------------------------------------------------------------------
// k_setup: blocks [0,354) = weight prep, blocks [354,8546) = LN1. (unchanged)
// ---------------------------------------------------------------------------
__global__ __launch_bounds__(256) void k_setup(
    const float* __restrict__ tok, const float* __restrict__ ln1g,
    const float* __restrict__ ln1b,
    const float* __restrict__ dW1, const float* __restrict__ db1,
    const float* __restrict__ rW1, const float* __restrict__ rb1,
    const float* __restrict__ rel, const float* __restrict__ dW2,
    const float* __restrict__ rW2, const float* __restrict__ vW,
    const float* __restrict__ vb,  const float* __restrict__ oW,
    USHORT* __restrict__ norm,
    USHORT* __restrict__ WnTg, USHORT* __restrict__ WcTg, USHORT* __restrict__ VTg,
    float* __restrict__ preg, float* __restrict__ vboWg, float* __restrict__ w2g)
{
    const int blk = blockIdx.x, t = threadIdx.x;
    if (blk >= 354) {                     // ---- LN1 ----
        const int p = (blk - 354) * 4 + (t >> 6);
        const int lane = t & 63;
        const float2 x = ((const float2*)(tok + (size_t)p * 128))[lane];
        float s = x.x + x.y;
        for (int m = 1; m < 64; m <<= 1) s += __shfl_xor(s, m);
        const float mean = s * (1.f / 128.f);
        const float d0 = x.x - mean, d1 = x.y - mean;
        float q = d0 * d0 + d1 * d1;
        for (int m = 1; m < 64; m <<= 1) q += __shfl_xor(q, m);
        const float rstd = rsqrtf(q * (1.f / 128.f) + 1e-5f);
        const float2 gg = ((const float2*)ln1g)[lane], bb = ((const float2*)ln1b)[lane];
        ((unsigned*)norm)[(size_t)p * 64 + lane] =
            (unsigned)f2bf(d0 * rstd * gg.x + bb.x) |
            ((unsigned)f2bf(d1 * rstd * gg.y + bb.y) << 16);
        return;
    }
    if (blk < 72) {                       // VTg [128][144] = perm(vW@oW)^T
        int idx = blk * 256 + t;
        int n = ((idx >> 4) * 7282) >> 16;
        int k = idx - n * 144;
        int r = k >> 4, tt = k & 15, c2 = r + 9 * tt;
        float acc = 0.f;
        if (c2 < 128)
            for (int j = 0; j < 128; ++j) acc += vW[c2 * 128 + j] * oW[j * 128 + n];
        VTg[idx] = f2bf(acc);
    } else if (blk < 216) {               // WnTg [256][144] = perm(W1b-W1c)^T
        int idx = (blk - 72) * 256 + t;
        int n = ((idx >> 4) * 7282) >> 16;
        int k = idx - n * 144;
        int r = k >> 4, tt = k & 15, c2 = r + 9 * tt;
        int col = n & 127;
        const float* W = (n < 128) ? dW1 : rW1;
        float val = 0.f;
        if (c2 < 128) val = W[(128 + c2) * 128 + col] - W[(256 + c2) * 128 + col];
        WnTg[idx] = f2bf(val);
    } else if (blk < 344) {               // WcTg [256][128] = (W1a+W1c)^T
        int idx = (blk - 216) * 256 + t;
        int n = idx >> 7, c = idx & 127, col = n & 127;
        const float* W = (n < 128) ? dW1 : rW1;
        WcTg[idx] = f2bf(W[c * 128 + col] + W[(256 + c) * 128 + col]);
    } else if (blk < 353) {               // preg[9][256] = rel@W1d + b1
        int n2 = blk - 344; int h = t;
        float acc;
        if (h < 128) {
            acc = db1[h];
            for (int r = 0; r < 8; ++r) acc += rel[n2 * 8 + r] * dW1[(384 + r) * 128 + h];
        } else {
            int hh = h - 128;
            acc = rb1[hh];
            for (int r = 0; r < 8; ++r) acc += rel[n2 * 8 + r] * rW1[(384 + r) * 128 + hh];
        }
        preg[n2 * 256 + h] = acc;
    } else {
        if (t < 128) {
            float acc = 0.f;
            for (int j = 0; j < 128; ++j) acc += vb[j] * oW[j * 128 + t];
            vboWg[t] = acc;
            w2g[t] = dW2[t];
            w2g[128 + t] = rW2[t];
        }
    }
}

// ---------------------------------------------------------------------------
// gather split (T14): issue global loads early into regs, LDS-write later.
// ---------------------------------------------------------------------------
__device__ __forceinline__ void gather_load(
    uint2 (&pf)[9], const USHORT* __restrict__ nb,
    int n2, int y, int bI, int tid)
{
    const int x = tid >> 2, q = tid & 3;
    #pragma unroll
    for (int r = 0; r < 9; ++r) {
        int u = 2 * n2 + r;
        int n = (u >= 18) ? (u - 18) : ((u >= 9) ? (u - 9) : u);
        int v = n2 * 128 + r;
        int c0 = (v * 7282) >> 16;                 // v/9
        int dyq = (n * 22) >> 6;                   // n/3
        int dx = n - 3 * dyq - 1;
        int dy = dyq - 1;
        int sy = y + dy, sx = x + dx;
        bool ok = ((unsigned)sy < 128u) && ((unsigned)sx < 128u);
        int e0 = (c0 & ~1) + 4 * q;
        size_t gidx = ((size_t)((bI * 128 + (ok ? sy : 0)) * 128 + (ok ? sx : 0))) * 128 + e0;
        const unsigned* gp = (const unsigned*)nb + (gidx >> 1);
        unsigned dw0 = gp[0], dw1 = gp[1];
        pf[r].x = ok ? dw0 : 0u;
        pf[r].y = ok ? dw1 : 0u;
    }
}

__device__ __forceinline__ void gather_store(
    USHORT* __restrict__ Adst, const uint2 (&pf)[9], int n2, int tid)
{
    const int x = tid >> 2, q = tid & 3;
    #pragma unroll
    for (int r = 0; r < 9; ++r) {
        int v = n2 * 128 + r;
        int c0 = (v * 7282) >> 16;
        unsigned dw0 = pf[r].x, dw1 = pf[r].y;
        unsigned nxt = (unsigned)__shfl_down((int)dw0, 1);   // feeds slot15 (zero-wt)
        unsigned o0, o1;
        if (c0 & 1) { o0 = (dw0 >> 16) | (dw1 << 16); o1 = (dw1 >> 16) | (nxt << 16); }
        else        { o0 = dw0;                       o1 = dw1; }
        *(uint2*)(Adst + x * AW + 16 * r + 4 * q) = make_uint2(o0, o1);
    }
}

// ---------------------------------------------------------------------------
// k_edge: 256 blocks (one image row each), 512 threads = 8 waves = 2M x 4N.
// MFMA 32x32x16 bf16; C/D: col=lane&31, row=(reg&3)+8*(reg>>2)+4*(lane>>5).
// LDS 159744 B: Wsh[256][152] | Ash0[128][152] | Ash1[128][152] | w2L |
//               dP[2][8][16] | rP[2][8][16] | gateL[128] | sgL[128]
// Loop barriers: A (partials written, prev G-accum reads of Anxt done),
//                B (gate + Anxt staged).  Post-loop: C, D, E.
// ---------------------------------------------------------------------------
__global__ __launch_bounds__(512, 2) void k_edge(
    const float* __restrict__ tok, const float* __restrict__ ln2g,
    const float* __restrict__ ln2b, const USHORT* __restrict__ nb,
    const USHORT* __restrict__ WnTg, const USHORT* __restrict__ WcTg,
    const USHORT* __restrict__ VTg, const float* __restrict__ preg,
    const float* __restrict__ vboWg, const float* __restrict__ w2g,
    const float* __restrict__ db2p, const float* __restrict__ rb2p,
    const float* __restrict__ gmp, const float* __restrict__ lmp,
    const float* __restrict__ bip, const float* __restrict__ obp,
    float* __restrict__ out)
{
    extern __shared__ char smem[];
    USHORT* Wsh  = (USHORT*)smem;                    // [256][152] = 77824
    USHORT* Ash0 = (USHORT*)(smem + 77824);          // [128][152] = 38912
    USHORT* Ash1 = (USHORT*)(smem + 116736);         // [128][152] = 38912
    float*  w2L  = (float*)(smem + 155648);          // 256 f32 = 1024
    float*  dP   = (float*)(smem + 156672);          // [2][8][16] f32 = 1024
    float*  rP   = (float*)(smem + 157696);          // [2][8][16] f32 = 1024
    float*  gateL= (float*)(smem + 158720);          // 128 f32 = 512
    float*  sgL  = (float*)(smem + 159232);          // end 159744
    float*  updF = (float*)smem;                     // final alias (64 KB, Wsh dead)

    const int tid = threadIdx.x;
    const int lane = tid & 63, wave = tid >> 6, hi = lane >> 5, l31 = lane & 31;
    const int mw = wave & 1, nw = wave >> 1;
    const int blk = blockIdx.x;
    const int bI = blk >> 7;
    const int y = ((blk & 7) << 4) | ((blk >> 3) & 15);   // XCD band swizzle
    const int p0 = (bI * 128 + y) * 128;

    // ---- stage Wc + center A + w2; zero sg ----
    for (int i = tid; i < 4096; i += 512) {
        int n = i >> 4, kv = i & 15;
        *(v8u*)(Wsh + n * AW + kv * 8) = *(const v8u*)(WcTg + n * 128 + kv * 8);
    }
    for (int i = tid; i < 2048; i += 512) {
        int x = i >> 4, kv = i & 15;
        *(v8u*)(Ash0 + x * AW + kv * 8) = *(const v8u*)(nb + (size_t)(p0 + x) * 128 + kv * 8);
    }
    if (tid < 256) w2L[tid] = w2g[tid];
    if (tid < 128) sgL[tid] = 0.f;
    __syncthreads();

    // ---- center GEMM (K=128): cp = center @ Wc ----
    v16f cp[2][2];
    #pragma unroll
    for (int a = 0; a < 2; ++a)
        for (int b = 0; b < 2; ++b)
            for (int e = 0; e < 16; ++e) cp[a][b][e] = 0.f;
    #pragma unroll
    for (int ks = 0; ks < 8; ++ks) {
        v8bf af0 = *(const v8bf*)(Ash0 + (mw * 64 + l31) * AW + ks * 16 + hi * 8);
        v8bf af1 = *(const v8bf*)(Ash0 + (mw * 64 + 32 + l31) * AW + ks * 16 + hi * 8);
        v8bf bf0 = *(const v8bf*)(Wsh + (nw * 64 + l31) * AW + ks * 16 + hi * 8);
        v8bf bf1 = *(const v8bf*)(Wsh + (nw * 64 + 32 + l31) * AW + ks * 16 + hi * 8);
        cp[0][0] = __builtin_amdgcn_mfma_f32_32x32x16_bf16(af0, bf0, cp[0][0], 0, 0, 0);
        cp[0][1] = __builtin_amdgcn_mfma_f32_32x32x16_bf16(af0, bf1, cp[0][1], 0, 0, 0);
        cp[1][0] = __builtin_amdgcn_mfma_f32_32x32x16_bf16(af1, bf0, cp[1][0], 0, 0, 0);
        cp[1][1] = __builtin_amdgcn_mfma_f32_32x32x16_bf16(af1, bf1, cp[1][1], 0, 0, 0);
    }
    __syncthreads();

    // ---- stage permuted Wn over Wc; first gather into Ash0 ----
    for (int i = tid; i < 4608; i += 512) {
        int n = (i * 3641) >> 16;                    // i/18
        int kv = i - n * 18;
        *(v8u*)(Wsh + n * AW + kv * 8) = *(const v8u*)(WnTg + n * 144 + kv * 8);
    }
    {
        uint2 pf0[9];
        gather_load(pf0, nb, 0, y, bI, tid);
        gather_store(Ash0, pf0, 0, tid);
    }

    const float gmv = gmp[0], lmv = lmp[0], biv = bip[0];
    const float db2v = db2p[0], rb2v = rb2p[0];
    const float wv0 = w2L[nw * 64 + l31];
    const float wv1 = w2L[nw * 64 + 32 + l31];

    // gated-sum accumulator: row = tid>>2, slots [(tid&3)*36, +36)
    float G[36];
    #pragma unroll
    for (int j = 0; j < 36; ++j) G[j] = 0.f;
    const int grow = tid >> 2, gq = tid & 3;

    // partial-sum slot base for this wave's lanes 31/63 (f32 index)
    float* sumBase = ((nw < 2) ? dP : rP) + (nw & 1) * 128;

    __syncthreads();                      // pre-loop: Wn + Ash0(0) ready

    for (int n2 = 0; n2 < 9; ++n2) {
        USHORT* Acur = (n2 & 1) ? Ash1 : Ash0;
        USHORT* Anxt = (n2 & 1) ? Ash0 : Ash1;
        const float pv0 = preg[n2 * 256 + nw * 64 + l31];
        const float pv1 = preg[n2 * 256 + nw * 64 + 32 + l31];

        // prefetch next tile's global loads — latency hides under MFMA
        uint2 pf[9];
        if (n2 < 8) gather_load(pf, nb, n2 + 1, y, bI, tid);

        // ---- edge GEMM: acc = cp + A_{n2} @ Wn (K'=144) ----
        v16f acc[2][2];
        #pragma unroll
        for (int a = 0; a < 2; ++a)
            for (int b = 0; b < 2; ++b) acc[a][b] = cp[a][b];
        #pragma unroll
        for (int ks = 0; ks < 9; ++ks) {
            v8bf af0 = *(const v8bf*)(Acur + (mw * 64 + l31) * AW + ks * 16 + hi * 8);
            v8bf af1 = *(const v8bf*)(Acur + (mw * 64 + 32 + l31) * AW + ks * 16 + hi * 8);
            v8bf bf0 = *(const v8bf*)(Wsh + (nw * 64 + l31) * AW + ks * 16 + hi * 8);
            v8bf bf1 = *(const v8bf*)(Wsh + (nw * 64 + 32 + l31) * AW + ks * 16 + hi * 8);
            acc[0][0] = __builtin_amdgcn_mfma_f32_32x32x16_bf16(af0, bf0, acc[0][0], 0, 0, 0);
            acc[0][1] = __builtin_amdgcn_mfma_f32_32x32x16_bf16(af0, bf1, acc[0][1], 0, 0, 0);
            acc[1][0] = __builtin_amdgcn_mfma_f32_32x32x16_bf16(af1, bf0, acc[1][0], 0, 0, 0);
            acc[1][1] = __builtin_amdgcn_mfma_f32_32x32x16_bf16(af1, bf1, acc[1][1], 0, 0, 0);
        }
        // ---- epilogue: gelu(h)·w2, DPP half-wave reduce, packed b128 write ----
        #pragma unroll
        for (int mt = 0; mt < 2; ++mt) {
            float part[16];
            #pragma unroll
            for (int rr = 0; rr < 16; ++rr) {
                float h0 = acc[mt][0][rr] + pv0;
                float h1 = acc[mt][1][rr] + pv1;
                float s0 = __builtin_amdgcn_rcpf(1.f + __expf(-1.702f * h0));
                float s1 = __builtin_amdgcn_rcpf(1.f + __expf(-1.702f * h1));
                part[rr] = h0 * s0 * wv0 + h1 * s1 * wv1;
            }
            #pragma unroll
            for (int rr = 0; rr < 16; ++rr) part[rr] = red32half(part[rr]);
            if (l31 == 31) {              // lanes 31 (hi=0) and 63 (hi=1)
                float* t0 = sumBase + ((mw * 2 + mt) * 2 + hi) * 16;
                *(float4*)(t0 +  0) = make_float4(part[0],  part[1],  part[2],  part[3]);
                *(float4*)(t0 +  4) = make_float4(part[4],  part[5],  part[6],  part[7]);
                *(float4*)(t0 +  8) = make_float4(part[8],  part[9],  part[10], part[11]);
                *(float4*)(t0 + 12) = make_float4(part[12], part[13], part[14], part[15]);
            }
        }
        __syncthreads();                  // A: partials written; prev G-accum
                                          //    reads of Anxt complete
        if (n2 < 8) gather_store(Anxt, pf, n2 + 1, tid);
        if (tid < 128) {
            // row t -> packed slot: slot=((mw*2+mt)*2+hi)*16+rr
            int w32 = tid & 31;
            int slot = (((tid >> 6) * 2 + ((tid >> 5) & 1)) * 2 + ((w32 >> 2) & 1)) * 16
                       + ((w32 & 3) | (((w32 >> 3) & 3) << 2));
            float d = dP[slot] + dP[128 + slot] + db2v;
            float rr = rP[slot] + rP[128 + slot] + rb2v;
            float sp = fmaxf(rr, 0.f) + log1pf(__expf(-fabsf(rr)));
            float e = gmv * d / (lmv * sp + 1e-6f) + biv;
            e = fminf(fmaxf(e, -3.f), 3.f);
            float gt = 1.f / (1.f + __expf(-e));
            gateL[tid] = gt; sgL[tid] += gt;
        }
        __syncthreads();                  // B: gate ready + Anxt staged
        // ---- G += g ⊙ A_{n2} (row-local gate broadcast, uint2 reads) ----
        {
            const float g = gateL[grow];
            const USHORT* Ar = Acur + grow * AW + gq * 36;
            #pragma unroll
            for (int j = 0; j < 9; ++j) {
                uint2 wv = *(const uint2*)(Ar + 4 * j);
                float v0 = __int_as_float((int)(wv.x << 16));
                float v1 = __int_as_float((int)(wv.x & 0xFFFF0000u));
                float v2 = __int_as_float((int)(wv.y << 16));
                float v3 = __int_as_float((int)(wv.y & 0xFFFF0000u));
                G[4 * j + 0] += g * v0;
                G[4 * j + 1] += g * v1;
                G[4 * j + 2] += g * v2;
                G[4 * j + 3] += g * v3;
            }
        }
    }

    __syncthreads();                      // C: loop reads done (Ash0/Ash1 free)

    // ---- G -> bf16 -> Ash0 ; stage VoW -> Ash1 ; mass ----
    {
        USHORT* dst = Ash0 + grow * AW + gq * 36;
        #pragma unroll
        for (int j = 0; j < 9; ++j) {
            unsigned lo = (unsigned)f2bf(G[4 * j + 0]) | ((unsigned)f2bf(G[4 * j + 1]) << 16);
            unsigned hi2 = (unsigned)f2bf(G[4 * j + 2]) | ((unsigned)f2bf(G[4 * j + 3]) << 16);
            *(uint2*)(dst + 4 * j) = make_uint2(lo, hi2);
        }
    }
    for (int i = tid; i < 2304; i += 512) {
        int n = (i * 3641) >> 16;                    // i/18
        int kv = i - n * 18;
        *(v8u*)(Ash1 + n * AW + kv * 8) = *(const v8u*)(VTg + n * 144 + kv * 8);
    }
    if (tid < 128) {
        float s = sgL[tid];
        float m = fmaxf(s, 1e-6f);
        dP[tid] = 1.f / m;       // 1/mass
        rP[tid] = s / m;         // sg/mass
    }
    __syncthreads();                      // D: G, VoW, mass visible

    // ---- message GEMM (once): P = G @ VoW, per-wave 32-col slice ----
    v16f P[2];
    #pragma unroll
    for (int a = 0; a < 2; ++a)
        for (int e = 0; e < 16; ++e) P[a][e] = 0.f;
    #pragma unroll
    for (int ks = 0; ks < 9; ++ks) {
        v8bf af0 = *(const v8bf*)(Ash0 + (mw * 64 + l31) * AW + ks * 16 + hi * 8);
        v8bf af1 = *(const v8bf*)(Ash0 + (mw * 64 + 32 + l31) * AW + ks * 16 + hi * 8);
        v8bf vf  = *(const v8bf*)(Ash1 + (nw * 32 + l31) * AW + ks * 16 + hi * 8);
        P[0] = __builtin_amdgcn_mfma_f32_32x32x16_bf16(af0, vf, P[0], 0, 0, 0);
        P[1] = __builtin_amdgcn_mfma_f32_32x32x16_bf16(af1, vf, P[1], 0, 0, 0);
    }

    // ---- final: update = P/mass + vboW*(sg/mass) + ob -> updF ----
    {
        const int colc = nw * 32 + l31;
        const float vbw = vboWg[colc], obv = obp[colc];
        #pragma unroll
        for (int mt = 0; mt < 2; ++mt) {
            const int base = mw * 64 + mt * 32 + 4 * hi;
            const float4* iq = (const float4*)&dP[base];
            const float4* sq = (const float4*)&rP[base];
            float4 ia = iq[0], ib = iq[2], ic = iq[4], id = iq[6];
            float4 sa = sq[0], sb = sq[2], sc = sq[4], sd = sq[6];
            float iv[16] = {ia.x, ia.y, ia.z, ia.w, ib.x, ib.y, ib.z, ib.w,
                            ic.x, ic.y, ic.z, ic.w, id.x, id.y, id.z, id.w};
            float sv[16] = {sa.x, sa.y, sa.z, sa.w, sb.x, sb.y, sb.z, sb.w,
                            sc.x, sc.y, sc.z, sc.w, sd.x, sd.y, sd.z, sd.w};
            #pragma unroll
            for (int rr = 0; rr < 16; ++rr) {
                int row = base + (rr & 3) + 8 * (rr >> 2);
                updF[row * 128 + colc] = P[mt][rr] * iv[rr] + vbw * sv[rr] + obv;
            }
        }
    }
    __syncthreads();                      // E: updF ready

    const float g20 = ln2g[lane], g21 = ln2g[lane + 64];
    const float b20 = ln2b[lane], b21 = ln2b[lane + 64];
    for (int q2 = 0; q2 < 16; ++q2) {
        int p = wave * 16 + q2;
        size_t gp = (size_t)(p0 + p) * 128;
        float x0 = tok[gp + lane]      + updF[p * 128 + lane];
        float x1 = tok[gp + lane + 64] + updF[p * 128 + lane + 64];
        float mean = bcast63(red64(x0 + x1)) * (1.f / 128.f);
        float d0 = x0 - mean, d1 = x1 - mean;
        float rstd = rsqrtf(bcast63(red64(d0 * d0 + d1 * d1)) * (1.f / 128.f) + 1e-5f);
        out[gp + lane]      = d0 * rstd * g20 + b20;
        out[gp + lane + 64] = d1 * rstd * g21 + b21;
    }
}

// ---------------------------------------------------------------------------
extern "C" void kernel_launch(void* const* d_in, const int* in_sizes, int n_in,
                              void* d_out, int out_size, void* d_ws, size_t ws_size,
                              hipStream_t stream) {
    const float* tok  = (const float*)d_in[0];
    const float* ln1g = (const float*)d_in[1];
    const float* ln1b = (const float*)d_in[2];
    const float* ln2g = (const float*)d_in[3];
    const float* ln2b = (const float*)d_in[4];
    const float* rel  = (const float*)d_in[5];
    const float* dW1  = (const float*)d_in[6];
    const float* db1  = (const float*)d_in[7];
    const float* dW2  = (const float*)d_in[8];
    const float* db2  = (const float*)d_in[9];
    const float* rW1  = (const float*)d_in[10];
    const float* rb1  = (const float*)d_in[11];
    const float* rW2  = (const float*)d_in[12];
    const float* rb2  = (const float*)d_in[13];
    const float* vW   = (const float*)d_in[14];
    const float* vb   = (const float*)d_in[15];
    const float* oW   = (const float*)d_in[16];
    const float* ob   = (const float*)d_in[17];
    const float* gm   = (const float*)d_in[18];
    const float* lm   = (const float*)d_in[19];
    const float* bi   = (const float*)d_in[20];
    float* out = (float*)d_out;

    char* w = (char*)d_ws;
    USHORT* norm = (USHORT*)w; w += 8388608;   // [32768][128] bf16
    USHORT* WnTg = (USHORT*)w; w += 73728;     // [256][144] bf16, permuted+zero-pad
    USHORT* WcTg = (USHORT*)w; w += 65536;     // [256][128] bf16
    USHORT* VTg  = (USHORT*)w; w += 36864;     // [128][144] bf16, permuted+zero-pad
    float*  preg = (float*)w;  w += 9216;      // [9][256] f32
    float*  vboWg= (float*)w;  w += 512;       // [128] f32
    float*  w2g  = (float*)w;  w += 1024;      // [256] f32

    hipFuncSetAttribute((const void*)k_edge,
                        hipFuncAttributeMaxDynamicSharedMemorySize, 159744);

    hipLaunchKernelGGL(k_setup, dim3(8546), dim3(256), 0, stream,
                       tok, ln1g, ln1b, dW1, db1, rW1, rb1, rel, dW2, rW2,
                       vW, vb, oW, norm, WnTg, WcTg, VTg, preg, vboWg, w2g);
    hipLaunchKernelGGL(k_edge, dim3(256), dim3(512), 159744, stream,
                       tok, ln2g, ln2b, norm, WnTg, WcTg, VTg, preg, vboWg, w2g,
                       db2, rb2, gm, lm, bi, ob, out);
}